// Round 1
// baseline (131.319 us; speedup 1.0000x reference)
//
#include <hip/hip_runtime.h>
#include <stdint.h>

// Problem constants (match reference)
#define B_ 4096
#define C_ 200
#define P_ 32
#define F_ 512
#define N_ (C_*P_)        // 6400 prototypes total
#define ALPHA_ 5.0
#define EPS_ 1e-8
#define NROWS_ (B_ + N_)  // 10496 sumsq rows (x2 then p2)

typedef unsigned char u8;
typedef __attribute__((ext_vector_type(4))) float floatx4;  // MFMA C/D frag
typedef __attribute__((ext_vector_type(8))) int   intx8;    // MX MFMA A/B frag (32B)

union frag32 { int4 v[2]; intx8 f; };   // 32 fp8 = one K=128 operand (virtual-K paired 16B units)

// ---------- prep: fp32 -> fp8 e4m3 packed + row sum-of-squares (x2 | p2) ----------
// Packed layout (unchanged): byte (tm*8+kc)*1024 + (q*16+r)*16 holds features
// [kc*64+q*16,+16) of row tm*16+r. One WAVE now owns one 16-row group (tm) and loops
// all 8 kc chunks, so the full row sumsq is produced in-register (two shfl_xor) and
// plain-stored: no atomics, no zero_kernel. 656 waves = 164 blocks.
__global__ void prep_kernel(const float* __restrict__ outputs, const float* __restrict__ clusters,
                            u8* __restrict__ At, u8* __restrict__ Bt, float* __restrict__ sumsq) {
    const int t    = blockIdx.x * 256 + threadIdx.x;
    const int wv   = t >> 6;            // global wave id: 0..255 -> A rows, 256..655 -> B rows
    const int lane = t & 63;
    const int q = lane >> 4, r = lane & 15;
    const float* src; u8* dst; int tm, rbase;
    if (wv < B_ / 16) { tm = wv;            src = outputs;  dst = At; rbase = 0;  }
    else              { tm = wv - B_ / 16;  src = clusters; dst = Bt; rbase = B_; }
    const int row = tm * 16 + r;

    float ss = 0.f;
#pragma unroll
    for (int kc = 0; kc < 8; ++kc) {
        const float4* s = (const float4*)(src + (size_t)row * F_ + kc * 64 + q * 16);
        float4 v0 = s[0], v1 = s[1], v2 = s[2], v3 = s[3];
        int4 w;
        w.x = __builtin_amdgcn_cvt_pk_fp8_f32(v0.x, v0.y, 0, false);
        w.x = __builtin_amdgcn_cvt_pk_fp8_f32(v0.z, v0.w, w.x, true);
        w.y = __builtin_amdgcn_cvt_pk_fp8_f32(v1.x, v1.y, 0, false);
        w.y = __builtin_amdgcn_cvt_pk_fp8_f32(v1.z, v1.w, w.y, true);
        w.z = __builtin_amdgcn_cvt_pk_fp8_f32(v2.x, v2.y, 0, false);
        w.z = __builtin_amdgcn_cvt_pk_fp8_f32(v2.z, v2.w, w.z, true);
        w.w = __builtin_amdgcn_cvt_pk_fp8_f32(v3.x, v3.y, 0, false);
        w.w = __builtin_amdgcn_cvt_pk_fp8_f32(v3.z, v3.w, w.w, true);
        *(int4*)(dst + (size_t)(tm * 8 + kc) * 1024 + (q * 16 + r) * 16) = w;

        ss += v0.x*v0.x + v0.y*v0.y + v0.z*v0.z + v0.w*v0.w
            + v1.x*v1.x + v1.y*v1.y + v1.z*v1.z + v1.w*v1.w
            + v2.x*v2.x + v2.y*v2.y + v2.z*v2.z + v2.w*v2.w
            + v3.x*v3.x + v3.y*v3.y + v3.z*v3.z + v3.w*v3.w;
    }
    ss += __shfl_xor(ss, 16);           // fold q^1
    ss += __shfl_xor(ss, 32);           // fold q^2 -> full row sum in every lane
    if (lane < 16) sumsq[rbase + row] = ss;
}

// ---------- score kernel: MX-scaled fp8 MFMA (K=128, unit scales), LDS dbuf ----------
// Same proven double-buffer/1-barrier-per-stage structure; K-stage = 128 features
// (two 64-feature chunks), consumed by mfma_scale_f32_16x16x128_f8f6f4 with E8M0
// scale 0x7F (=2^0) so numerics == non-scaled fp8 at 2x the MFMA rate (ladder m148).
#define BM 128
#define BN 128

typedef const __attribute__((address_space(1))) unsigned int gu32_t;
typedef __attribute__((address_space(3))) unsigned int lu32_t;

__device__ __forceinline__ void gld16(const u8* g, u8* l) {
    __builtin_amdgcn_global_load_lds((gu32_t*)g, (lu32_t*)l, 16, 0, 0);
}

__global__ __launch_bounds__(256, 2)
void score_kernel(const u8* __restrict__ At, const u8* __restrict__ Bt,
                  const float* __restrict__ p2, float* __restrict__ min_d) {
    // [buf][ A: 8 subtiles x 2 chunks x 1KB | B: same ] = 2 x 32KB
    __shared__ __align__(16) u8 lds[2][32768];

    const int tid  = threadIdx.x;
    const int lane = tid & 63;
    const int w    = tid >> 6;          // wave 0..3 (2x2 wave grid, 64x64 per wave)
    const int wm   = w >> 1, wn = w & 1;
    const int bx   = blockIdx.x;        // n-tile 0..49
    const int by   = blockIdx.y;        // m-tile 0..31
    const int m0   = by * BM, n0 = bx * BN;
    const int mrow = lane & 15;
    const int quad = lane >> 4;
    const int l16  = lane * 16;

    const u8* ag = At + ((size_t)(by * 8) << 13);   // 8 row-subtiles x 8KB each
    const u8* bg = Bt + ((size_t)(bx * 8) << 13);

    floatx4 zf = {0.f, 0.f, 0.f, 0.f};
    floatx4 acc[4][4];
#pragma unroll
    for (int i = 0; i < 4; ++i)
#pragma unroll
        for (int j = 0; j < 4; ++j) acc[i][j] = zf;

    // prologue: prefetch stage 0 (chunks 0,1) into buf 0
#pragma unroll
    for (int c = 0; c < 2; ++c) {
        gld16(ag + ((w * 8 + c) << 10) + l16,         lds[0] + (w * 2 + c) * 1024);
        gld16(ag + (((w + 4) * 8 + c) << 10) + l16,   lds[0] + ((w + 4) * 2 + c) * 1024);
        gld16(bg + ((w * 8 + c) << 10) + l16,         lds[0] + 16384 + (w * 2 + c) * 1024);
        gld16(bg + (((w + 4) * 8 + c) << 10) + l16,   lds[0] + 16384 + ((w + 4) * 2 + c) * 1024);
    }
    __syncthreads();

#pragma unroll
    for (int s = 0; s < 4; ++s) {
        const int cur = s & 1;
        if (s < 3) {
            const int nb = cur ^ 1;
#pragma unroll
            for (int c = 0; c < 2; ++c) {
                const int kn = 2 * (s + 1) + c;
                gld16(ag + ((w * 8 + kn) << 10) + l16,         lds[nb] + (w * 2 + c) * 1024);
                gld16(ag + (((w + 4) * 8 + kn) << 10) + l16,   lds[nb] + ((w + 4) * 2 + c) * 1024);
                gld16(bg + ((w * 8 + kn) << 10) + l16,         lds[nb] + 16384 + (w * 2 + c) * 1024);
                gld16(bg + (((w + 4) * 8 + kn) << 10) + l16,   lds[nb] + 16384 + ((w + 4) * 2 + c) * 1024);
            }
        }
        frag32 a[4], b[4];
#pragma unroll
        for (int t = 0; t < 4; ++t) {
            const int ta = (wm * 4 + t) * 2, tb = (wn * 4 + t) * 2;
            a[t].v[0] = *(const int4*)(lds[cur] + (ta    ) * 1024 + l16);
            a[t].v[1] = *(const int4*)(lds[cur] + (ta + 1) * 1024 + l16);
            b[t].v[0] = *(const int4*)(lds[cur] + 16384 + (tb    ) * 1024 + l16);
            b[t].v[1] = *(const int4*)(lds[cur] + 16384 + (tb + 1) * 1024 + l16);
        }
#pragma unroll
        for (int mt = 0; mt < 4; ++mt)
#pragma unroll
            for (int nt = 0; nt < 4; ++nt)
                acc[mt][nt] = __builtin_amdgcn_mfma_scale_f32_16x16x128_f8f6f4(
                    a[mt].f, b[nt].f, acc[mt][nt],
                    0, 0,                       // cbsz=FP8(e4m3), blgp=FP8(e4m3)
                    0, 0x7F7F7F7F,              // opsel_a, scale_a = E8M0 127 -> x1.0
                    0, 0x7F7F7F7F);             // opsel_b, scale_b
        __syncthreads();
    }

    // Epilogue: score = p2[n] - 2*xp. Only the min VALUE per class is needed.
    // C/D layout (shape-determined, same as 16x16x32): col = lane&15, row = quad*4 + reg.
    float pg[4];
#pragma unroll
    for (int nt = 0; nt < 4; ++nt) pg[nt] = p2[n0 + wn * 64 + nt * 16 + mrow];

#pragma unroll
    for (int ch = 0; ch < 2; ++ch) {
        const int cls = bx * 4 + wn * 2 + ch;
#pragma unroll
        for (int mt = 0; mt < 4; ++mt)
#pragma unroll
            for (int reg = 0; reg < 4; ++reg) {
                float v = fminf(pg[ch * 2]     - 2.0f * acc[mt][ch * 2][reg],
                                pg[ch * 2 + 1] - 2.0f * acc[mt][ch * 2 + 1][reg]);
#pragma unroll
                for (int m = 8; m >= 1; m >>= 1) v = fminf(v, __shfl_xor(v, m));
                if (mrow == 0) {
                    int grow = m0 + wm * 64 + mt * 16 + quad * 4 + reg;
                    min_d[grow * C_ + cls] = v;
                }
            }
    }
}

// ---------- per-sample: target value + masked min over wrong classes (values only) ----------
__global__ void select_kernel(const float* __restrict__ min_d, const float* __restrict__ x2,
                              const int* __restrict__ tgt,
                              float* __restrict__ stw, float* __restrict__ sww) {
    int b    = blockIdx.x * 4 + (threadIdx.x >> 6);
    int lane = threadIdx.x & 63;
    int tc   = tgt[b];
    const float* row = min_d + (size_t)b * C_;

    float vt = row[tc];          // broadcast load
    float bw = 3.4e38f;
    for (int c = lane; c < C_; c += 64) {
        float v = row[c];
        if (c != tc) bw = fminf(bw, v);
    }
#pragma unroll
    for (int m = 32; m >= 1; m >>= 1) bw = fminf(bw, __shfl_xor(bw, m));
    if (lane == 0) {
        float xx = x2[b];
        stw[b] = xx + vt;        // = ||x - p_target*||^2 (fp8-dot approx)
        sww[b] = xx + bw;        // = ||x - p_wrong*||^2
    }
}

// Single-block reduction of 2x4096 floats + final loss
__global__ __launch_bounds__(1024)
void finalize_kernel(const float* __restrict__ stw, const float* __restrict__ sww,
                     float* __restrict__ out) {
    __shared__ float r1[16], r2[16];
    int tid = threadIdx.x;
    float s1 = 0.f, s2 = 0.f;
#pragma unroll
    for (int i = 0; i < 4; ++i) {
        s1 += stw[tid + i * 1024];
        s2 += sww[tid + i * 1024];
    }
#pragma unroll
    for (int m = 32; m >= 1; m >>= 1) { s1 += __shfl_xor(s1, m); s2 += __shfl_xor(s2, m); }
    if ((tid & 63) == 0) { r1[tid >> 6] = s1; r2[tid >> 6] = s2; }
    __syncthreads();
    if (tid == 0) {
        double t1 = 0.0, t2 = 0.0;
#pragma unroll
        for (int i = 0; i < 16; ++i) { t1 += (double)r1[i]; t2 += (double)r2[i]; }
        double denom = (double)B_ * (double)F_;
        double tl  = t1 / denom;
        double ntl = t2 / denom;
        out[0] = (float)((1.0 - ALPHA_) * tl + ALPHA_ / (ntl + EPS_));
    }
}

// ---------- launch ----------
extern "C" void kernel_launch(void* const* d_in, const int* in_sizes, int n_in,
                              void* d_out, int out_size, void* d_ws, size_t ws_size,
                              hipStream_t stream) {
    const float* outputs  = (const float*)d_in[0];
    const float* clusters = (const float*)d_in[1];
    const int*   tgt      = (const int*)d_in[2];
    float* out = (float*)d_out;

    char* ws = (char*)d_ws;
    // workspace layout (16B-aligned), total 8,692,736 bytes
    u8*     At      = (u8*)(ws);                     // packed A: 2,097,152
    u8*     Bt      = (u8*)(ws + 2097152);           // packed B: 3,276,800
    float*  sumsq   = (float*)(ws + 5373952);        // 10496*4 = 41,984 (x2 | p2)
    float*  min_d   = (float*)(ws + 5415936);        // 4096*200*4 = 3,276,800
    float*  x2      = sumsq;
    float*  p2      = sumsq + B_;
    // per-sample partials: reuse the At region (dead after score_kernel)
    float*  stw     = (float*)(ws);                  // 4096*4
    float*  sww     = (float*)(ws + 16384);          // 4096*4

    prep_kernel<<<(B_ / 16 + N_ / 16) * 64 / 256, 256, 0, stream>>>(outputs, clusters, At, Bt, sumsq); // 164
    score_kernel<<<dim3(N_ / BN, B_ / BM), 256, 0, stream>>>(At, Bt, p2, min_d);            // 50x32
    select_kernel<<<B_ / 4, 256, 0, stream>>>(min_d, x2, tgt, stw, sww);                    // 1024
    finalize_kernel<<<1, 1024, 0, stream>>>(stw, sww, out);
}